// Round 1
// 605.710 us; speedup vs baseline: 1.2564x; 1.2564x over previous
//
#include <hip/hip_runtime.h>

// ---------------------------------------------------------------------------
// Grouped MLP: h1 = x @ W1^T + b1 ; out = h1 @ W2^T + b2, per group g in [0,8)
// x  [8, 2048, 1024] f32    W1 [8, 4096, 1024] f32   b1 [8, 4096] f32
// W2 [8, 1024, 4096] f32    b2 [8, 1024] f32         out [8, 2048, 1024] f32
//
// This version: 256x256x(BK=64) bf16 MFMA GEMM with the 8-phase counted-vmcnt
// schedule (T1 XCD swizzle + T2 LDS XOR swizzle + T3/T4 phase pipeline with
// vmcnt(4) + T5 setprio).  LDS = 128 KiB: 2 buffers x {A,B} x {k0,k1} planes,
// each plane [256][32] bf16 (16 KiB), staged one plane per phase.
// ---------------------------------------------------------------------------

typedef __bf16 bf16_t;
typedef bf16_t bf16x8 __attribute__((ext_vector_type(8)));
typedef float  floatx4 __attribute__((ext_vector_type(4)));

#define NUM_GEMMS 8
#define HIDDEN 1024
#define INTER 4096
#define MTOK 2048

__device__ __forceinline__ void async_copy16(const bf16_t* gsrc, bf16_t* lds_base) {
  // LDS dest is wave-uniform base + lane*16 (HW semantics); pass wave base.
  __builtin_amdgcn_global_load_lds(
      (const __attribute__((address_space(1))) void*)gsrc,
      (__attribute__((address_space(3))) void*)lds_base,
      16, 0, 0);
}

// fp32 -> bf16, 8 elements/thread, three segments fused in one launch.
__global__ __launch_bounds__(256) void cvt3_kernel(
    const float* __restrict__ s0, bf16_t* __restrict__ d0, long n0,
    const float* __restrict__ s1, bf16_t* __restrict__ d1, long n1,
    const float* __restrict__ s2, bf16_t* __restrict__ d2, long n2) {
  long i = (long)blockIdx.x * 256 + threadIdx.x;
  const float* s;
  bf16_t* d;
  if (i < n0) {
    s = s0; d = d0;
  } else if (i < n0 + n1) {
    i -= n0; s = s1; d = d1;
  } else {
    i -= n0 + n1; s = s2; d = d2;
    if (i >= n2) return;
  }
  const float4* s4 = (const float4*)s;
  float4 a = s4[2 * i];
  float4 b = s4[2 * i + 1];
  bf16x8 o;
  o[0] = (bf16_t)a.x; o[1] = (bf16_t)a.y; o[2] = (bf16_t)a.z; o[3] = (bf16_t)a.w;
  o[4] = (bf16_t)b.x; o[5] = (bf16_t)b.y; o[6] = (bf16_t)b.z; o[7] = (bf16_t)b.w;
  *(bf16x8*)(d + i * 8) = o;
}

#define BAR() __builtin_amdgcn_s_barrier()
#define WAITVM(n) asm volatile("s_waitcnt vmcnt(" #n ")" ::: "memory")

// C[g,m,n] = sum_k A[g,m,k] * B[g,n,k] + bias[g,n]
// 256x256 tile, BK=64, 512 threads (8 waves as 2x4, each wave 128x64 out).
template <int M, int N, int K, bool OUT_BF16>
__global__ __launch_bounds__(512, 2) void gemm256(const bf16_t* __restrict__ A,
                                                  const bf16_t* __restrict__ B,
                                                  const float* __restrict__ bias,
                                                  void* __restrict__ Cout) {
  constexpr int BM = 256, BN = 256, BK = 64;
  constexpr int NT = K / BK;          // K tiles (16 or 64; always even, >= 4)
  constexpr int MB = M / BM, NB = N / BN;
  constexpr int PL = 256 * 32;        // plane elems (16 KiB)

  // planes: idx = buf*4 + mat*2 + ks   (mat: 0=A, 1=B; ks: k-half)
  __shared__ __align__(16) bf16_t lds[8 * PL];  // 128 KiB

  // ---- T1: bijective XCD swizzle (nwg % 8 == 0 for both GEMMs) ----
  const int nwg = gridDim.x;
  const int cpx = nwg >> 3;
  int bid = blockIdx.x;
  bid = (bid & 7) * cpx + (bid >> 3);
  constexpr int perG = MB * NB;
  const int g   = bid / perG;
  const int rem = bid % perG;
  const int m0 = (rem % MB) * BM;   // m fastest: consecutive ids share B panel
  const int n0 = (rem / MB) * BN;

  const bf16_t* Ag = A + (size_t)g * M * K;
  const bf16_t* Bg = B + (size_t)g * N * K;

  const int t    = threadIdx.x;
  const int lane = t & 63;
  const int wave = t >> 6;
  const int wr   = wave >> 2;   // 0..1  -> rows [wr*128, +128)
  const int wc   = wave & 3;    // 0..3  -> cols [wc*64, +64)
  const int l16  = lane & 15;
  const int q    = lane >> 4;

  // ---- T2 swizzle: LDS slot (row r, chunk j') holds global chunk j'^((r>>1)&3).
  // Reader side: per-thread swizzled chunk (row mod 16 == l16 always).
  const int jj = q ^ ((l16 >> 1) & 3);
  const int aBase = (wr * 128 + l16) * 32 + jj * 8;  // + mh*2048 + i*512
  const int bBase = (wc * 64 + l16) * 32 + jj * 8;   // + j*512

  // Writer side: thread t covers LDS chunks t and t+512 of the staged plane.
  // chunk c -> row r=c>>2, slot j'=c&3, global chunk j = j' ^ ((r>>1)&3).
  const int sr = t >> 2;                       // 0..127 (and +128 for chunk 2)
  const int sj = (t & 3) ^ ((t >> 3) & 3);     // same for both chunks
  const bf16_t* pA1 = Ag + (size_t)(m0 + sr) * K + sj * 8;
  const bf16_t* pA2 = pA1 + (size_t)128 * K;
  const bf16_t* pB1 = Bg + (size_t)(n0 + sr) * K + sj * 8;
  const bf16_t* pB2 = pB1 + (size_t)128 * K;
  bf16_t* ldsW = lds + wave * 512;  // wave-uniform write base (+plane offset)

#define STAGE(mat, ks, ktile, bufv)                                         \
  do {                                                                      \
    const size_t _ko = (size_t)(ktile) * BK + (ks) * 32;                    \
    const bf16_t* _s1 = ((mat) == 0 ? pA1 : pB1) + _ko;                     \
    const bf16_t* _s2 = ((mat) == 0 ? pA2 : pB2) + _ko;                     \
    bf16_t* _d = ldsW + ((bufv) * 4 + (mat) * 2 + (ks)) * PL;               \
    async_copy16(_s1, _d);                                                  \
    async_copy16(_s2, _d + 4096);                                           \
  } while (0)

#define LDA4(dst, bufc, ks, mh)                                             \
  _Pragma("unroll") for (int i = 0; i < 4; ++i)                             \
      dst[i] = *(const bf16x8*)(lds + ((bufc) * 4 + (ks)) * PL + aBase +    \
                                (mh) * 2048 + i * 512);

#define LDB4(dst, bufc, ks)                                                 \
  _Pragma("unroll") for (int j = 0; j < 4; ++j)                             \
      dst[j] = *(const bf16x8*)(lds + ((bufc) * 4 + 2 + (ks)) * PL +        \
                                bBase + j * 512);

#define MFMA16(i0, afv, bfv)                                                \
  __builtin_amdgcn_s_setprio(1);                                            \
  _Pragma("unroll") for (int i = 0; i < 4; ++i)                             \
  _Pragma("unroll") for (int j = 0; j < 4; ++j)                             \
      acc[(i0) + i][j] = __builtin_amdgcn_mfma_f32_16x16x32_bf16(           \
          afv[i], bfv[j], acc[(i0) + i][j], 0, 0, 0);                       \
  __builtin_amdgcn_s_setprio(0);

  floatx4 acc[8][4];
  const floatx4 z = {0.0f, 0.0f, 0.0f, 0.0f};
#pragma unroll
  for (int i = 0; i < 8; ++i)
#pragma unroll
    for (int j = 0; j < 4; ++j) acc[i][j] = z;

  // ---- prologue: tile0 all 4 planes + tile1 k0 planes; keep 2 stages in flight
  STAGE(0, 0, 0, 0);
  STAGE(1, 0, 0, 0);
  STAGE(0, 1, 0, 0);
  STAGE(1, 1, 0, 0);
  STAGE(0, 0, 1, 1);
  STAGE(1, 0, 1, 1);
  WAITVM(4);  // tile0 fully in LDS; tile1 k0 (4 loads) still in flight
  BAR();

  // Per tile: 4 phases {(mh0,k0),(mh1,k0),(mh0,k1),(mh1,k1)}, each 16 MFMA.
  // Stages: p1/p2 -> k1 planes of tile kt+1 (other buf); p3/p4 -> k0 planes of
  // tile kt+2 (this buf; slots freed after p2/p1 of this tile).
  // vmcnt(4) at p4 retires everything except p3/p4's own stages -> all data
  // for the next tile's 4 phases is resident. Never drains to 0 mid-loop.
#define TILE(ktv, bufc)                                                     \
  do {                                                                      \
    const int kt_ = (ktv);                                                  \
    bf16x8 af[4], b0[4], b1[4];                                             \
    /* p1: (mh0, k0) */                                                     \
    LDB4(b0, bufc, 0);                                                      \
    LDA4(af, bufc, 0, 0);                                                   \
    if (kt_ + 1 < NT) STAGE(0, 1, kt_ + 1, (bufc) ^ 1);                     \
    BAR();                                                                  \
    MFMA16(0, af, b0);                                                      \
    BAR();                                                                  \
    /* p2: (mh1, k0) */                                                     \
    LDA4(af, bufc, 0, 1);                                                   \
    if (kt_ + 1 < NT) STAGE(1, 1, kt_ + 1, (bufc) ^ 1);                     \
    BAR();                                                                  \
    MFMA16(4, af, b0);                                                      \
    BAR();                                                                  \
    /* p3: (mh0, k1) */                                                     \
    LDB4(b1, bufc, 1);                                                      \
    LDA4(af, bufc, 1, 0);                                                   \
    if (kt_ + 2 < NT) STAGE(0, 0, kt_ + 2, bufc);                           \
    BAR();                                                                  \
    MFMA16(0, af, b1);                                                      \
    BAR();                                                                  \
    /* p4: (mh1, k1) */                                                     \
    LDA4(af, bufc, 1, 1);                                                   \
    if (kt_ + 2 < NT) STAGE(1, 0, kt_ + 2, bufc);                           \
    BAR();                                                                  \
    MFMA16(4, af, b1);                                                      \
    if (kt_ < NT - 2) {                                                     \
      WAITVM(4);                                                            \
    } else {                                                                \
      WAITVM(0);                                                            \
    }                                                                       \
    BAR();                                                                  \
  } while (0)

#pragma unroll 1
  for (int kt = 0; kt < NT; kt += 2) {
    TILE(kt, 0);
    TILE(kt + 1, 1);
  }

  // ---- epilogue: C/D layout col = lane&15, row = quad*4 + reg (m89/m91) ----
  const float* bg = bias + (size_t)g * N;
  float* Cf = (float*)Cout;
  bf16_t* Cb = (bf16_t*)Cout;
#pragma unroll
  for (int j = 0; j < 4; ++j) {
    const int n = n0 + wc * 64 + j * 16 + l16;
    const float bv = bg[n];
#pragma unroll
    for (int i = 0; i < 8; ++i) {
      const int mr = m0 + wr * 128 + i * 16 + q * 4;
#pragma unroll
      for (int r = 0; r < 4; ++r) {
        const float v = acc[i][j][r] + bv;
        const size_t idx = (size_t)g * M * N + (size_t)(mr + r) * N + n;
        if constexpr (OUT_BF16)
          Cb[idx] = (bf16_t)v;
        else
          Cf[idx] = v;
      }
    }
  }
#undef TILE
#undef MFMA16
#undef LDB4
#undef LDA4
#undef STAGE
}

extern "C" void kernel_launch(void* const* d_in, const int* in_sizes, int n_in,
                              void* d_out, int out_size, void* d_ws, size_t ws_size,
                              hipStream_t stream) {
  const float* x  = (const float*)d_in[0];
  const float* W1 = (const float*)d_in[1];
  const float* b1 = (const float*)d_in[2];
  const float* W2 = (const float*)d_in[3];
  const float* b2 = (const float*)d_in[4];
  float* out = (float*)d_out;

  const size_t nx  = (size_t)NUM_GEMMS * MTOK * HIDDEN;   // 16.7M
  const size_t nw1 = (size_t)NUM_GEMMS * INTER * HIDDEN;  // 33.5M
  const size_t nw2 = nw1;                                 // 33.5M

  // ws layout (bf16): xb | w1b | w2b | h1
  bf16_t* xb  = (bf16_t*)d_ws;
  bf16_t* w1b = xb + nx;
  bf16_t* w2b = w1b + nw1;
  bf16_t* h1  = w2b + nw2;

  const long c0 = (long)(nx / 8), c1 = (long)(nw1 / 8), c2 = (long)(nw2 / 8);
  const unsigned cvtBlocks = (unsigned)((c0 + c1 + c2 + 255) / 256);
  cvt3_kernel<<<dim3(cvtBlocks), dim3(256), 0, stream>>>(x, xb, c0, W1, w1b, c1,
                                                         W2, w2b, c2);

  // GEMM1: M=2048, N=4096(INTER), K=1024(HIDDEN) -> h1 (bf16). grid=1024
  gemm256<MTOK, INTER, HIDDEN, true>
      <<<dim3((MTOK / 256) * (INTER / 256) * NUM_GEMMS), dim3(512), 0, stream>>>(
          xb, w1b, b1, (void*)h1);

  // GEMM2: M=2048, N=1024(HIDDEN), K=4096(INTER) -> out (fp32). grid=256
  gemm256<MTOK, HIDDEN, INTER, false>
      <<<dim3((MTOK / 256) * (HIDDEN / 256) * NUM_GEMMS), dim3(512), 0, stream>>>(
          h1, w2b, b2, (void*)out);
}